// Round 1
// baseline (465.374 us; speedup 1.0000x reference)
//
#include <hip/hip_runtime.h>
#include <cstdint>
#include <cstddef>

typedef __attribute__((ext_vector_type(4))) int   i32x4;
typedef __attribute__((ext_vector_type(4))) float f32x4;

// Problem dims (fixed by setup_inputs: B=8, S=2048, K=4096, O=4096)
#define M_DIM 16384
#define N_DIM 4096
#define K_DIM 4096

// ---------------------------------------------------------------------------
// quantize x (per-tensor): xq = clip(rint(x/s)+zp, -128,127) - zp
// 16 elements per thread, vectorized f32x4 loads, 16B int8 store.
// ---------------------------------------------------------------------------
__global__ __launch_bounds__(256) void quant_x_kernel(
    const float* __restrict__ x,
    const float* __restrict__ act_scale,
    const int*   __restrict__ act_zp,
    signed char* __restrict__ xq)
{
    int idx = blockIdx.x * 256 + threadIdx.x;      // one thread per 16 elems
    float s   = act_scale[0];
    float zpf = (float)act_zp[0];
    const f32x4* xp = (const f32x4*)(x + (size_t)idx * 16);
    union { signed char c[16]; i32x4 v; } u;
#pragma unroll
    for (int j = 0; j < 4; ++j) {
        f32x4 v = xp[j];
#pragma unroll
        for (int e = 0; e < 4; ++e) {
            float q = rintf(v[e] / s) + zpf;          // round-half-even like np.round
            q = fminf(fmaxf(q, -128.f), 127.f);
            u.c[j * 4 + e] = (signed char)(int)(q - zpf);
        }
    }
    *(i32x4*)(xq + (size_t)idx * 16) = u.v;
}

// ---------------------------------------------------------------------------
// quantize weight (per-output-row scale/zp). K_DIM=4096 -> 256 threads/row.
// ---------------------------------------------------------------------------
__global__ __launch_bounds__(256) void quant_w_kernel(
    const float* __restrict__ w,
    const float* __restrict__ wscale,
    const int*   __restrict__ wzp,
    signed char* __restrict__ wq)
{
    int idx = blockIdx.x * 256 + threadIdx.x;      // one thread per 16 elems
    int row = idx >> 8;                             // 4096/16 = 256 chunks per row
    float s   = wscale[row];
    float zpf = (float)wzp[row];
    const f32x4* wp = (const f32x4*)(w + (size_t)idx * 16);
    union { signed char c[16]; i32x4 v; } u;
#pragma unroll
    for (int j = 0; j < 4; ++j) {
        f32x4 v = wp[j];
#pragma unroll
        for (int e = 0; e < 4; ++e) {
            float q = rintf(v[e] / s) + zpf;
            q = fminf(fmaxf(q, -128.f), 127.f);
            u.c[j * 4 + e] = (signed char)(int)(q - zpf);
        }
    }
    *(i32x4*)(wq + (size_t)idx * 16) = u.v;
}

// ---------------------------------------------------------------------------
// int8 GEMM, m97 structure: 128x128 tile, BK=64 (64B LDS rows), 256 threads
// = 4 waves (2x2), each wave 64x64 out = 4x4 frags of 16x16.
// A = xq [M,K] row-major, B = wq [O,K] row-major (i.e. B^T input layout).
// C[m][o] = sum_k A[m,k]*B[o,k]; epilogue: out = acc * (sa*sw[o]) + bias[o].
// ---------------------------------------------------------------------------
__global__ __launch_bounds__(256, 2) void gemm_i8_kernel(
    const signed char* __restrict__ Aq,
    const signed char* __restrict__ Bq,
    const float* __restrict__ bias,
    const float* __restrict__ act_scale,
    const float* __restrict__ wscale,
    float* __restrict__ out)
{
    __shared__ signed char As[128 * 64];   // 8 KiB
    __shared__ signed char Bs[128 * 64];   // 8 KiB

    const int nbn = N_DIM / 128;                 // 32
    const int nwg = (M_DIM / 128) * nbn;         // 4096 (%8==0 -> simple swizzle ok)
    int bid = blockIdx.x;
    int wg  = (bid & 7) * (nwg >> 3) + (bid >> 3);  // XCD-aware swizzle, bijective
    int bm  = wg / nbn;
    int bn  = wg % nbn;

    int tid  = threadIdx.x;
    int wave = tid >> 6;
    int lane = tid & 63;
    int wm = (wave >> 1) * 64;
    int wn = (wave & 1) * 64;

    const signed char* Ag = Aq + (size_t)bm * 128 * K_DIM;
    const signed char* Bg = Bq + (size_t)bn * 128 * K_DIM;

    // staging: tile is 128 rows x 64B = 8192B; 256 thr * 16B = 4096B/inst -> 2 insts
    int off0 = tid * 16;             // 0..4095   (rows 0..63)
    int off1 = off0 + 4096;          // 4096..8191 (rows 64..127)
    int r0 = off0 >> 6, c0 = off0 & 63;
    int r1 = off1 >> 6, c1 = off1 & 63;
    // wave-uniform LDS bases (global_load_lds writes base + lane*16)
    signed char* lA0 = As + wave * 1024;
    signed char* lA1 = As + 4096 + wave * 1024;
    signed char* lB0 = Bs + wave * 1024;
    signed char* lB1 = Bs + 4096 + wave * 1024;

    i32x4 acc[4][4] = {};

    int lr = lane & 15;               // frag row
    int lk = (lane >> 4) * 16;        // byte offset within 64B row

    for (int k0 = 0; k0 < K_DIM; k0 += 64) {
        __builtin_amdgcn_global_load_lds(
            (const __attribute__((address_space(1))) void*)(Ag + (size_t)r0 * K_DIM + k0 + c0),
            (__attribute__((address_space(3))) void*)lA0, 16, 0, 0);
        __builtin_amdgcn_global_load_lds(
            (const __attribute__((address_space(1))) void*)(Ag + (size_t)r1 * K_DIM + k0 + c1),
            (__attribute__((address_space(3))) void*)lA1, 16, 0, 0);
        __builtin_amdgcn_global_load_lds(
            (const __attribute__((address_space(1))) void*)(Bg + (size_t)r0 * K_DIM + k0 + c0),
            (__attribute__((address_space(3))) void*)lB0, 16, 0, 0);
        __builtin_amdgcn_global_load_lds(
            (const __attribute__((address_space(1))) void*)(Bg + (size_t)r1 * K_DIM + k0 + c1),
            (__attribute__((address_space(3))) void*)lB1, 16, 0, 0);
        __syncthreads();   // compiler inserts vmcnt(0) drain before barrier

        i32x4 af[4], bf[4];
#pragma unroll
        for (int m = 0; m < 4; ++m)
            af[m] = *(const i32x4*)(As + (wm + m * 16 + lr) * 64 + lk);
#pragma unroll
        for (int n = 0; n < 4; ++n)
            bf[n] = *(const i32x4*)(Bs + (wn + n * 16 + lr) * 64 + lk);

#pragma unroll
        for (int m = 0; m < 4; ++m)
#pragma unroll
            for (int n = 0; n < 4; ++n)
                acc[m][n] = __builtin_amdgcn_mfma_i32_16x16x64_i8(af[m], bf[n], acc[m][n], 0, 0, 0);

        __syncthreads();   // all waves done reading before next stage overwrites
    }

    // epilogue: out = acc * (sa * sw[o]) + bias[o]
    float sa = act_scale[0];
    int colb = lane & 15;
    int rsub = (lane >> 4) * 4;
#pragma unroll
    for (int n = 0; n < 4; ++n) {
        int o = bn * 128 + wn + n * 16 + colb;
        float sw = sa * wscale[o];
        float bv = bias[o];
#pragma unroll
        for (int m = 0; m < 4; ++m) {
            int grow = bm * 128 + wm + m * 16 + rsub;
#pragma unroll
            for (int r = 0; r < 4; ++r) {
                out[(size_t)(grow + r) * N_DIM + o] = (float)acc[m][n][r] * sw + bv;
            }
        }
    }
}

// ---------------------------------------------------------------------------
// insurance fallback if ws_size < 80MB (should never trigger): direct qdq GEMM
// ---------------------------------------------------------------------------
__global__ void fallback_kernel(
    const float* __restrict__ x, const float* __restrict__ w,
    const float* __restrict__ bias,
    const float* __restrict__ act_scale, const float* __restrict__ wscale,
    const int* __restrict__ act_zp, const int* __restrict__ wzp,
    float* __restrict__ out)
{
    size_t idx = (size_t)blockIdx.x * blockDim.x + threadIdx.x;
    if (idx >= (size_t)M_DIM * N_DIM) return;
    int m = (int)(idx >> 12);       // /4096
    int o = (int)(idx & 4095);
    float sx = act_scale[0], zx = (float)act_zp[0];
    float sw = wscale[o],    zw = (float)wzp[o];
    float acc = 0.f;
    for (int k = 0; k < K_DIM; ++k) {
        float qx = fminf(fmaxf(rintf(x[(size_t)m * K_DIM + k] / sx) + zx, -128.f), 127.f) - zx;
        float qw = fminf(fmaxf(rintf(w[(size_t)o * K_DIM + k] / sw) + zw, -128.f), 127.f) - zw;
        acc += (qx * sx) * (qw * sw);
    }
    out[idx] = acc + bias[o];
}

// ---------------------------------------------------------------------------
extern "C" void kernel_launch(void* const* d_in, const int* in_sizes, int n_in,
                              void* d_out, int out_size, void* d_ws, size_t ws_size,
                              hipStream_t stream)
{
    const float* x    = (const float*)d_in[0];
    const float* w    = (const float*)d_in[1];
    const float* bias = (const float*)d_in[2];
    const float* asc  = (const float*)d_in[3];
    const float* wsc  = (const float*)d_in[4];
    const int*   azp  = (const int*)d_in[5];
    const int*   wzp  = (const int*)d_in[6];
    float* out = (float*)d_out;

    size_t xq_bytes = (size_t)M_DIM * K_DIM;   // 64 MiB
    size_t wq_bytes = (size_t)N_DIM * K_DIM;   // 16 MiB

    if (ws_size < xq_bytes + wq_bytes) {
        int total = M_DIM * N_DIM;
        fallback_kernel<<<(total + 255) / 256, 256, 0, stream>>>(
            x, w, bias, asc, wsc, azp, wzp, out);
        return;
    }

    signed char* xq = (signed char*)d_ws;
    signed char* wq = (signed char*)d_ws + xq_bytes;

    quant_x_kernel<<<(M_DIM * (K_DIM / 16)) / 256, 256, 0, stream>>>(x, asc, azp, xq);
    quant_w_kernel<<<(N_DIM * (K_DIM / 16)) / 256, 256, 0, stream>>>(w, wsc, wzp, wq);
    gemm_i8_kernel<<<(M_DIM / 128) * (N_DIM / 128), 256, 0, stream>>>(
        xq, wq, bias, asc, wsc, out);
}

// Round 2
// 377.816 us; speedup vs baseline: 1.2317x; 1.2317x over previous
//
#include <hip/hip_runtime.h>
#include <cstdint>
#include <cstddef>

typedef __attribute__((ext_vector_type(4))) int   i32x4;
typedef __attribute__((ext_vector_type(4))) float f32x4;

// Problem dims (fixed by setup_inputs: B=8, S=2048, K=4096, O=4096)
#define M_DIM 16384
#define N_DIM 4096
#define K_DIM 4096
#define NT    (K_DIM / 128)   // 32 K-tiles of 128 int8 (= 2 MFMA K-steps each)

// ---------------------------------------------------------------------------
// quantize x (per-tensor): xq = clip(rint(x/s)+zp, -128,127) - zp
// ---------------------------------------------------------------------------
__global__ __launch_bounds__(256) void quant_x_kernel(
    const float* __restrict__ x,
    const float* __restrict__ act_scale,
    const int*   __restrict__ act_zp,
    signed char* __restrict__ xq)
{
    int idx = blockIdx.x * 256 + threadIdx.x;      // one thread per 16 elems
    float s   = act_scale[0];
    float zpf = (float)act_zp[0];
    const f32x4* xp = (const f32x4*)(x + (size_t)idx * 16);
    union { signed char c[16]; i32x4 v; } u;
#pragma unroll
    for (int j = 0; j < 4; ++j) {
        f32x4 v = xp[j];
#pragma unroll
        for (int e = 0; e < 4; ++e) {
            float q = rintf(v[e] / s) + zpf;          // round-half-even like np.round
            q = fminf(fmaxf(q, -128.f), 127.f);
            u.c[j * 4 + e] = (signed char)(int)(q - zpf);
        }
    }
    *(i32x4*)(xq + (size_t)idx * 16) = u.v;
}

// ---------------------------------------------------------------------------
// quantize weight (per-output-row scale/zp). K_DIM=4096 -> 256 threads/row.
// ---------------------------------------------------------------------------
__global__ __launch_bounds__(256) void quant_w_kernel(
    const float* __restrict__ w,
    const float* __restrict__ wscale,
    const int*   __restrict__ wzp,
    signed char* __restrict__ wq)
{
    int idx = blockIdx.x * 256 + threadIdx.x;
    int row = idx >> 8;                             // 4096/16 = 256 chunks per row
    float s   = wscale[row];
    float zpf = (float)wzp[row];
    const f32x4* wp = (const f32x4*)(w + (size_t)idx * 16);
    union { signed char c[16]; i32x4 v; } u;
#pragma unroll
    for (int j = 0; j < 4; ++j) {
        f32x4 v = wp[j];
#pragma unroll
        for (int e = 0; e < 4; ++e) {
            float q = rintf(v[e] / s) + zpf;
            q = fminf(fmaxf(q, -128.f), 127.f);
            u.c[j * 4 + e] = (signed char)(int)(q - zpf);
        }
    }
    *(i32x4*)(wq + (size_t)idx * 16) = u.v;
}

// ---------------------------------------------------------------------------
// int8 GEMM, 256x256 8-phase template (T1+T2+T3/T4+T5) ported to i8.
// BK = 128 i8 bytes/row (byte-identical addressing to the verified bf16 BK=64
// template; mfma_i32_16x16x64_i8 fragment = 16B/lane like bf16 16x16x32).
// 512 threads = 8 waves (2M x 4N), per-wave output 128x64 (8 mf x 4 nf frags).
// LDS 128 KiB: 2 dbuf x (A 256x128B + B 256x128B).
// st_16x32 swizzle: byte ^= ((byte>>9)&1)<<5  (linear LDS dest for
// global_load_lds + inverse-swizzled per-lane GLOBAL source; swizzled ds_read).
//
// Per K-tile (4 phases), quad order (0,0),(0,1),(1,1),(1,0); reads 12/4/8/0;
// b0 held in regs across the tile. Staging order per K-tile [B0,B1,A0,A1]:
// phase p issues half-tile h=4t+6+p -> p0:(t+1,A0) p1:(t+1,A1) [other buf],
// p2:(t+2,B0) p3:(t+2,B1) [current buf; B reads complete at p1's end barrier,
// so the overwrite-issue at p2 is race-free]. Counted vmcnt(4) at tile
// boundary (2 half-tiles = 4 loads/wave in flight), never 0 in steady state.
// ---------------------------------------------------------------------------
__global__ __launch_bounds__(512, 2) void gemm_i8_256(
    const signed char* __restrict__ Aq,
    const signed char* __restrict__ Bq,
    const float* __restrict__ bias,
    const float* __restrict__ act_scale,
    const float* __restrict__ wscale,
    float* __restrict__ out)
{
    __shared__ signed char lds[131072];   // 128 KiB -> 1 block/CU, 2 waves/SIMD

    const int nbn = N_DIM / 256;                 // 16
    const int nwg = (M_DIM / 256) * nbn;         // 1024, %8==0 -> simple swizzle ok
    int bid = blockIdx.x;
    int wg  = (bid & 7) * (nwg >> 3) + (bid >> 3);   // T1 XCD swizzle, bijective
    int bm  = wg / nbn;
    int bn  = wg % nbn;

    int tid  = threadIdx.x;
    int wave = tid >> 6;
    int lane = tid & 63;
    int wm_i = wave >> 2;      // 0..1
    int wn_i = wave & 3;       // 0..3

    const signed char* Ag = Aq + (size_t)bm * 256 * K_DIM;
    const signed char* Bg = Bq + (size_t)bn * 256 * K_DIM;

    // staging: pre-swizzled per-lane GLOBAL source offsets (LDS dest stays linear)
    int soff0, soff1;
    { int o = tid * 16;        o ^= ((o >> 9) & 1) << 5; soff0 = (o >> 7) * K_DIM + (o & 127); }
    { int o = 8192 + tid * 16; o ^= ((o >> 9) & 1) << 5; soff1 = (o >> 7) * K_DIM + (o & 127); }

    // reader fragment bases, swizzle folded in (bit9 of frag addr == lane bit2)
    int xmask = ((lane >> 2) & 1) << 5;
    int abase = (((wm_i * 128 + (lane & 15)) * 128) + ((lane >> 4) * 16)) ^ xmask;
    int bbase = ((32768 + (wn_i * 64 + (lane & 15)) * 128) + ((lane >> 4) * 16)) ^ xmask;

    // pos: 0=B-half0, 1=B-half1, 2=A-half0, 3=A-half1
#define STAGE(tile, pos) do {                                                        \
    const signed char* _src = (((pos) < 2)                                           \
        ? (Bg + (size_t)((pos) * 128) * K_DIM)                                       \
        : (Ag + (size_t)(((pos) - 2) * 128) * K_DIM)) + (size_t)(tile) * 128;        \
    int _ldso = ((tile) & 1) * 65536                                                 \
              + (((pos) < 2) ? (32768 + (pos) * 16384) : (((pos) - 2) * 16384))      \
              + wave * 1024;                                                         \
    __builtin_amdgcn_global_load_lds(                                                \
        (const __attribute__((address_space(1))) void*)(_src + soff0),               \
        (__attribute__((address_space(3))) void*)(lds + _ldso), 16, 0, 0);           \
    __builtin_amdgcn_global_load_lds(                                                \
        (const __attribute__((address_space(1))) void*)(_src + soff1),               \
        (__attribute__((address_space(3))) void*)(lds + _ldso + 8192), 16, 0, 0);    \
} while (0)

    i32x4 acc[8][4] = {};
    i32x4 a0[4][2], a1[4][2], b0[2][2], b1[2][2];

    // prologue: tile0 fully + tile1 B0,B1  (12 loads/wave in flight)
    STAGE(0, 0); STAGE(0, 1); STAGE(0, 2); STAGE(0, 3);
    STAGE(1, 0); STAGE(1, 1);
    asm volatile("s_waitcnt vmcnt(4)" ::: "memory");   // tile0's 8 loads landed
    __builtin_amdgcn_s_barrier();

    for (int t = 0; t < NT; ++t) {
        const signed char* buf = lds + (t & 1) * 65536;

        // ---------------- phase 0: read A0 + B0, compute quad(0,0) ----------
#pragma unroll
        for (int mf = 0; mf < 4; ++mf)
#pragma unroll
            for (int kk = 0; kk < 2; ++kk)
                a0[mf][kk] = *(const i32x4*)(buf + abase + mf * 2048 + kk * 64);
#pragma unroll
        for (int nf = 0; nf < 2; ++nf)
#pragma unroll
            for (int kk = 0; kk < 2; ++kk)
                b0[nf][kk] = *(const i32x4*)(buf + bbase + nf * 2048 + kk * 64);
        if (t + 1 < NT) STAGE(t + 1, 2);
        __builtin_amdgcn_s_barrier();
        __builtin_amdgcn_s_setprio(1);
#pragma unroll
        for (int mf = 0; mf < 4; ++mf)
#pragma unroll
            for (int nf = 0; nf < 2; ++nf)
#pragma unroll
                for (int kk = 0; kk < 2; ++kk)
                    acc[mf][nf] = __builtin_amdgcn_mfma_i32_16x16x64_i8(
                        a0[mf][kk], b0[nf][kk], acc[mf][nf], 0, 0, 0);
        __builtin_amdgcn_s_setprio(0);
        __builtin_amdgcn_s_barrier();

        // ---------------- phase 1: read B1, compute quad(0,1) ---------------
#pragma unroll
        for (int nf = 0; nf < 2; ++nf)
#pragma unroll
            for (int kk = 0; kk < 2; ++kk)
                b1[nf][kk] = *(const i32x4*)(buf + bbase + (2 + nf) * 2048 + kk * 64);
        if (t + 1 < NT) STAGE(t + 1, 3);
        __builtin_amdgcn_s_barrier();
        __builtin_amdgcn_s_setprio(1);
#pragma unroll
        for (int mf = 0; mf < 4; ++mf)
#pragma unroll
            for (int nf = 0; nf < 2; ++nf)
#pragma unroll
                for (int kk = 0; kk < 2; ++kk)
                    acc[mf][2 + nf] = __builtin_amdgcn_mfma_i32_16x16x64_i8(
                        a0[mf][kk], b1[nf][kk], acc[mf][2 + nf], 0, 0, 0);
        __builtin_amdgcn_s_setprio(0);
        __builtin_amdgcn_s_barrier();

        // ---------------- phase 2: read A1, compute quad(1,1) ---------------
#pragma unroll
        for (int mf = 0; mf < 4; ++mf)
#pragma unroll
            for (int kk = 0; kk < 2; ++kk)
                a1[mf][kk] = *(const i32x4*)(buf + abase + (4 + mf) * 2048 + kk * 64);
        if (t + 2 < NT) STAGE(t + 2, 0);
        __builtin_amdgcn_s_barrier();
        __builtin_amdgcn_s_setprio(1);
#pragma unroll
        for (int mf = 0; mf < 4; ++mf)
#pragma unroll
            for (int nf = 0; nf < 2; ++nf)
#pragma unroll
                for (int kk = 0; kk < 2; ++kk)
                    acc[4 + mf][2 + nf] = __builtin_amdgcn_mfma_i32_16x16x64_i8(
                        a1[mf][kk], b1[nf][kk], acc[4 + mf][2 + nf], 0, 0, 0);
        __builtin_amdgcn_s_setprio(0);
        __builtin_amdgcn_s_barrier();

        // ---------------- phase 3: no reads, compute quad(1,0) --------------
        if (t + 2 < NT) STAGE(t + 2, 1);
        __builtin_amdgcn_s_barrier();
        __builtin_amdgcn_s_setprio(1);
#pragma unroll
        for (int mf = 0; mf < 4; ++mf)
#pragma unroll
            for (int nf = 0; nf < 2; ++nf)
#pragma unroll
                for (int kk = 0; kk < 2; ++kk)
                    acc[4 + mf][nf] = __builtin_amdgcn_mfma_i32_16x16x64_i8(
                        a1[mf][kk], b0[nf][kk], acc[4 + mf][nf], 0, 0, 0);
        __builtin_amdgcn_s_setprio(0);
        // tile boundary: counted drain (never 0 in steady state), then barrier
        if (t < NT - 2) {
            asm volatile("s_waitcnt vmcnt(4)" ::: "memory");
            __builtin_amdgcn_s_barrier();
        } else if (t == NT - 2) {
            asm volatile("s_waitcnt vmcnt(0)" ::: "memory");
            __builtin_amdgcn_s_barrier();
        }
        // t == NT-1: fall through to epilogue
    }
#undef STAGE

    // epilogue: out = acc * (sa * sw[o]) + bias[o]
    float sa = act_scale[0];
    int colb = lane & 15;
    int rsub = (lane >> 4) * 4;
#pragma unroll
    for (int nf = 0; nf < 4; ++nf) {
        int o = bn * 256 + wn_i * 64 + nf * 16 + colb;
        float sw = sa * wscale[o];
        float bv = bias[o];
#pragma unroll
        for (int mf = 0; mf < 8; ++mf) {
            int grow = bm * 256 + wm_i * 128 + mf * 16 + rsub;
#pragma unroll
            for (int r = 0; r < 4; ++r)
                out[(size_t)(grow + r) * N_DIM + o] = (float)acc[mf][nf][r] * sw + bv;
        }
    }
}

// ---------------------------------------------------------------------------
// insurance fallback if ws_size < 80MB (should never trigger)
// ---------------------------------------------------------------------------
__global__ void fallback_kernel(
    const float* __restrict__ x, const float* __restrict__ w,
    const float* __restrict__ bias,
    const float* __restrict__ act_scale, const float* __restrict__ wscale,
    const int* __restrict__ act_zp, const int* __restrict__ wzp,
    float* __restrict__ out)
{
    size_t idx = (size_t)blockIdx.x * blockDim.x + threadIdx.x;
    if (idx >= (size_t)M_DIM * N_DIM) return;
    int m = (int)(idx >> 12);
    int o = (int)(idx & 4095);
    float sx = act_scale[0], zx = (float)act_zp[0];
    float sw = wscale[o],    zw = (float)wzp[o];
    float acc = 0.f;
    for (int k = 0; k < K_DIM; ++k) {
        float qx = fminf(fmaxf(rintf(x[(size_t)m * K_DIM + k] / sx) + zx, -128.f), 127.f) - zx;
        float qw = fminf(fmaxf(rintf(w[(size_t)o * K_DIM + k] / sw) + zw, -128.f), 127.f) - zw;
        acc += (qx * sx) * (qw * sw);
    }
    out[idx] = acc + bias[o];
}

// ---------------------------------------------------------------------------
extern "C" void kernel_launch(void* const* d_in, const int* in_sizes, int n_in,
                              void* d_out, int out_size, void* d_ws, size_t ws_size,
                              hipStream_t stream)
{
    const float* x    = (const float*)d_in[0];
    const float* w    = (const float*)d_in[1];
    const float* bias = (const float*)d_in[2];
    const float* asc  = (const float*)d_in[3];
    const float* wsc  = (const float*)d_in[4];
    const int*   azp  = (const int*)d_in[5];
    const int*   wzp  = (const int*)d_in[6];
    float* out = (float*)d_out;

    size_t xq_bytes = (size_t)M_DIM * K_DIM;   // 64 MiB
    size_t wq_bytes = (size_t)N_DIM * K_DIM;   // 16 MiB

    if (ws_size < xq_bytes + wq_bytes) {
        int total = M_DIM * N_DIM;
        fallback_kernel<<<(total + 255) / 256, 256, 0, stream>>>(
            x, w, bias, asc, wsc, azp, wzp, out);
        return;
    }

    signed char* xq = (signed char*)d_ws;
    signed char* wq = (signed char*)d_ws + xq_bytes;

    quant_x_kernel<<<(M_DIM * (K_DIM / 16)) / 256, 256, 0, stream>>>(x, asc, azp, xq);
    quant_w_kernel<<<(N_DIM * (K_DIM / 16)) / 256, 256, 0, stream>>>(w, wsc, wzp, wq);
    gemm_i8_256<<<(M_DIM / 256) * (N_DIM / 256), 512, 0, stream>>>(
        xq, wq, bias, asc, wsc, out);
}

// Round 3
// 363.682 us; speedup vs baseline: 1.2796x; 1.0389x over previous
//
#include <hip/hip_runtime.h>
#include <cstdint>
#include <cstddef>

typedef __attribute__((ext_vector_type(4))) int   i32x4;
typedef __attribute__((ext_vector_type(4))) float f32x4;

// Problem dims (fixed by setup_inputs: B=8, S=2048, K=4096, O=4096)
#define M_DIM 16384
#define N_DIM 4096
#define K_DIM 4096
#define NT    (K_DIM / 128)   // 32 K-tiles of 128 int8 (= 2 MFMA K-steps each)

// ---------------------------------------------------------------------------
// quantize x (per-tensor): xq = clip(rint(x/s)+zp, -128,127) - zp
// ---------------------------------------------------------------------------
__global__ __launch_bounds__(256) void quant_x_kernel(
    const float* __restrict__ x,
    const float* __restrict__ act_scale,
    const int*   __restrict__ act_zp,
    signed char* __restrict__ xq)
{
    int idx = blockIdx.x * 256 + threadIdx.x;      // one thread per 16 elems
    float s   = act_scale[0];
    float zpf = (float)act_zp[0];
    const f32x4* xp = (const f32x4*)(x + (size_t)idx * 16);
    union { signed char c[16]; i32x4 v; } u;
#pragma unroll
    for (int j = 0; j < 4; ++j) {
        f32x4 v = xp[j];
#pragma unroll
        for (int e = 0; e < 4; ++e) {
            float q = rintf(v[e] / s) + zpf;          // round-half-even like np.round
            q = fminf(fmaxf(q, -128.f), 127.f);
            u.c[j * 4 + e] = (signed char)(int)(q - zpf);
        }
    }
    *(i32x4*)(xq + (size_t)idx * 16) = u.v;
}

// ---------------------------------------------------------------------------
// quantize weight (per-output-row scale/zp). K_DIM=4096 -> 256 threads/row.
// ---------------------------------------------------------------------------
__global__ __launch_bounds__(256) void quant_w_kernel(
    const float* __restrict__ w,
    const float* __restrict__ wscale,
    const int*   __restrict__ wzp,
    signed char* __restrict__ wq)
{
    int idx = blockIdx.x * 256 + threadIdx.x;
    int row = idx >> 8;                             // 4096/16 = 256 chunks per row
    float s   = wscale[row];
    float zpf = (float)wzp[row];
    const f32x4* wp = (const f32x4*)(w + (size_t)idx * 16);
    union { signed char c[16]; i32x4 v; } u;
#pragma unroll
    for (int j = 0; j < 4; ++j) {
        f32x4 v = wp[j];
#pragma unroll
        for (int e = 0; e < 4; ++e) {
            float q = rintf(v[e] / s) + zpf;
            q = fminf(fmaxf(q, -128.f), 127.f);
            u.c[j * 4 + e] = (signed char)(int)(q - zpf);
        }
    }
    *(i32x4*)(wq + (size_t)idx * 16) = u.v;
}

// ---------------------------------------------------------------------------
// int8 GEMM, 256x256 8-phase template (T1+T2+T3/T4+T5) ported to i8.
// BK = 128 i8 bytes/row. 512 threads = 8 waves (2M x 4N), per-wave 128x64 out.
// LDS 128 KiB: 2 dbuf x (A 256x128B + B 256x128B).
//
// T2 swizzle (FULL 3-bit, per G4): addr ^= (row&7)<<4. Lanes 0-7 of each
// ds_read_b128 then cover all 8 distinct 16B slots = all 32 banks exactly
// once -> balanced at any HW phase quantum. row&7 == lane&7 on both A and B
// reads, so the mask is a per-lane constant; it commutes with mf*2048
// (bits>=11) so it's folded into per-kk bases. Stage side: LDS dest stays
// LINEAR (global_load_lds requirement), global source column is
// inverse-swizzled: c = ((tid&7)*16) ^ (((tid>>3)&7)<<4).
//
// Per K-tile (4 phases), quad order (0,0),(0,1),(1,1),(1,0); reads 12/4/8/0;
// b0 held in regs across the tile. Staging per K-tile [B0,B1,A0,A1]:
// p0:(t+1,A0) p1:(t+1,A1) [other buf], p2:(t+2,B0) p3:(t+2,B1) [current buf;
// B reads complete at p1's end barrier -> race-free]. Counted vmcnt(4) at
// tile boundary, never 0 in steady state.
// ---------------------------------------------------------------------------
__global__ __launch_bounds__(512, 2) void gemm_i8_256(
    const signed char* __restrict__ Aq,
    const signed char* __restrict__ Bq,
    const float* __restrict__ bias,
    const float* __restrict__ act_scale,
    const float* __restrict__ wscale,
    float* __restrict__ out)
{
    __shared__ signed char lds[131072];   // 128 KiB -> 1 block/CU, 2 waves/SIMD

    const int nbn = N_DIM / 256;                 // 16
    const int nwg = (M_DIM / 256) * nbn;         // 1024, %8==0 -> simple swizzle ok
    int bid = blockIdx.x;
    int wg  = (bid & 7) * (nwg >> 3) + (bid >> 3);   // T1 XCD swizzle, bijective
    int bm  = wg / nbn;
    int bn  = wg % nbn;

    int tid  = threadIdx.x;
    int wave = tid >> 6;
    int lane = tid & 63;
    int wm_i = wave >> 2;      // 0..1
    int wn_i = wave & 3;       // 0..3

    const signed char* Ag = Aq + (size_t)bm * 256 * K_DIM;
    const signed char* Bg = Bq + (size_t)bn * 256 * K_DIM;

    // staging: linear LDS dest; inverse-swizzled per-lane GLOBAL source.
    // LDS byte (row*128 + col) holds global (row, col ^ ((row&7)<<4)).
    int srow = tid >> 3;
    int scol = ((tid & 7) * 16) ^ ((srow & 7) << 4);
    int soff0 = srow * K_DIM + scol;            // rows 0..63 of half-tile
    int soff1 = (srow + 64) * K_DIM + scol;     // rows 64..127 (64%8==0: same mask)

    // reader fragment bases with 3-bit swizzle folded in.
    // linear frag addr = region + row*128 + lk + kk*64;  row&7 == lane&7.
    int lk = (lane >> 4) * 16;
    int xm = (lane & 7) << 4;
    int arow = wm_i * 128 + (lane & 15);
    int brow = wn_i * 64 + (lane & 15);
    int ab0 = (arow * 128 + lk) ^ xm;                    // kk=0
    int ab1 = (arow * 128 + lk + 64) ^ xm;               // kk=1 (bit6 toggles pre-XOR)
    int bb0 = (32768 + brow * 128 + lk) ^ xm;
    int bb1 = (32768 + brow * 128 + lk + 64) ^ xm;
    // + mf*2048 / nf*2048 only touches bits >=11 -> commutes with the XOR.

    // pos: 0=B-half0, 1=B-half1, 2=A-half0, 3=A-half1
#define STAGE(tile, pos) do {                                                        \
    const signed char* _src = (((pos) < 2)                                           \
        ? (Bg + (size_t)((pos) * 128) * K_DIM)                                       \
        : (Ag + (size_t)(((pos) - 2) * 128) * K_DIM)) + (size_t)(tile) * 128;        \
    int _ldso = ((tile) & 1) * 65536                                                 \
              + (((pos) < 2) ? (32768 + (pos) * 16384) : (((pos) - 2) * 16384))      \
              + wave * 1024;                                                         \
    __builtin_amdgcn_global_load_lds(                                                \
        (const __attribute__((address_space(1))) void*)(_src + soff0),               \
        (__attribute__((address_space(3))) void*)(lds + _ldso), 16, 0, 0);           \
    __builtin_amdgcn_global_load_lds(                                                \
        (const __attribute__((address_space(1))) void*)(_src + soff1),               \
        (__attribute__((address_space(3))) void*)(lds + _ldso + 8192), 16, 0, 0);    \
} while (0)

    i32x4 acc[8][4] = {};
    i32x4 a0[4][2], a1[4][2], b0[2][2], b1[2][2];

    // prologue: tile0 fully + tile1 B0,B1  (12 loads/wave in flight)
    STAGE(0, 0); STAGE(0, 1); STAGE(0, 2); STAGE(0, 3);
    STAGE(1, 0); STAGE(1, 1);
    asm volatile("s_waitcnt vmcnt(4)" ::: "memory");   // tile0's 8 loads landed
    __builtin_amdgcn_s_barrier();

    for (int t = 0; t < NT; ++t) {
        const signed char* buf = lds + (t & 1) * 65536;

        // ---------------- phase 0: read A0 + B0, compute quad(0,0) ----------
#pragma unroll
        for (int mf = 0; mf < 4; ++mf) {
            a0[mf][0] = *(const i32x4*)(buf + ab0 + mf * 2048);
            a0[mf][1] = *(const i32x4*)(buf + ab1 + mf * 2048);
        }
#pragma unroll
        for (int nf = 0; nf < 2; ++nf) {
            b0[nf][0] = *(const i32x4*)(buf + bb0 + nf * 2048);
            b0[nf][1] = *(const i32x4*)(buf + bb1 + nf * 2048);
        }
        if (t + 1 < NT) STAGE(t + 1, 2);
        __builtin_amdgcn_s_barrier();
        __builtin_amdgcn_s_setprio(1);
#pragma unroll
        for (int mf = 0; mf < 4; ++mf)
#pragma unroll
            for (int nf = 0; nf < 2; ++nf)
#pragma unroll
                for (int kk = 0; kk < 2; ++kk)
                    acc[mf][nf] = __builtin_amdgcn_mfma_i32_16x16x64_i8(
                        a0[mf][kk], b0[nf][kk], acc[mf][nf], 0, 0, 0);
        __builtin_amdgcn_s_setprio(0);
        __builtin_amdgcn_s_barrier();

        // ---------------- phase 1: read B1, compute quad(0,1) ---------------
#pragma unroll
        for (int nf = 0; nf < 2; ++nf) {
            b1[nf][0] = *(const i32x4*)(buf + bb0 + (2 + nf) * 2048);
            b1[nf][1] = *(const i32x4*)(buf + bb1 + (2 + nf) * 2048);
        }
        if (t + 1 < NT) STAGE(t + 1, 3);
        __builtin_amdgcn_s_barrier();
        __builtin_amdgcn_s_setprio(1);
#pragma unroll
        for (int mf = 0; mf < 4; ++mf)
#pragma unroll
            for (int nf = 0; nf < 2; ++nf)
#pragma unroll
                for (int kk = 0; kk < 2; ++kk)
                    acc[mf][2 + nf] = __builtin_amdgcn_mfma_i32_16x16x64_i8(
                        a0[mf][kk], b1[nf][kk], acc[mf][2 + nf], 0, 0, 0);
        __builtin_amdgcn_s_setprio(0);
        __builtin_amdgcn_s_barrier();

        // ---------------- phase 2: read A1, compute quad(1,1) ---------------
#pragma unroll
        for (int mf = 0; mf < 4; ++mf) {
            a1[mf][0] = *(const i32x4*)(buf + ab0 + (4 + mf) * 2048);
            a1[mf][1] = *(const i32x4*)(buf + ab1 + (4 + mf) * 2048);
        }
        if (t + 2 < NT) STAGE(t + 2, 0);
        __builtin_amdgcn_s_barrier();
        __builtin_amdgcn_s_setprio(1);
#pragma unroll
        for (int mf = 0; mf < 4; ++mf)
#pragma unroll
            for (int nf = 0; nf < 2; ++nf)
#pragma unroll
                for (int kk = 0; kk < 2; ++kk)
                    acc[4 + mf][2 + nf] = __builtin_amdgcn_mfma_i32_16x16x64_i8(
                        a1[mf][kk], b1[nf][kk], acc[4 + mf][2 + nf], 0, 0, 0);
        __builtin_amdgcn_s_setprio(0);
        __builtin_amdgcn_s_barrier();

        // ---------------- phase 3: no reads, compute quad(1,0) --------------
        if (t + 2 < NT) STAGE(t + 2, 1);
        __builtin_amdgcn_s_barrier();
        __builtin_amdgcn_s_setprio(1);
#pragma unroll
        for (int mf = 0; mf < 4; ++mf)
#pragma unroll
            for (int nf = 0; nf < 2; ++nf)
#pragma unroll
                for (int kk = 0; kk < 2; ++kk)
                    acc[4 + mf][nf] = __builtin_amdgcn_mfma_i32_16x16x64_i8(
                        a1[mf][kk], b0[nf][kk], acc[4 + mf][nf], 0, 0, 0);
        __builtin_amdgcn_s_setprio(0);
        // tile boundary: counted drain (never 0 in steady state), then barrier
        if (t < NT - 2) {
            asm volatile("s_waitcnt vmcnt(4)" ::: "memory");
            __builtin_amdgcn_s_barrier();
        } else if (t == NT - 2) {
            asm volatile("s_waitcnt vmcnt(0)" ::: "memory");
            __builtin_amdgcn_s_barrier();
        }
        // t == NT-1: fall through to epilogue
    }
#undef STAGE

    // epilogue: out = acc * (sa * sw[o]) + bias[o]
    float sa = act_scale[0];
    int colb = lane & 15;
    int rsub = (lane >> 4) * 4;
#pragma unroll
    for (int nf = 0; nf < 4; ++nf) {
        int o = bn * 256 + wn_i * 64 + nf * 16 + colb;
        float sw = sa * wscale[o];
        float bv = bias[o];
#pragma unroll
        for (int mf = 0; mf < 8; ++mf) {
            int grow = bm * 256 + wm_i * 128 + mf * 16 + rsub;
#pragma unroll
            for (int r = 0; r < 4; ++r)
                out[(size_t)(grow + r) * N_DIM + o] = (float)acc[mf][nf][r] * sw + bv;
        }
    }
}

// ---------------------------------------------------------------------------
// insurance fallback if ws_size < 80MB (should never trigger)
// ---------------------------------------------------------------------------
__global__ void fallback_kernel(
    const float* __restrict__ x, const float* __restrict__ w,
    const float* __restrict__ bias,
    const float* __restrict__ act_scale, const float* __restrict__ wscale,
    const int* __restrict__ act_zp, const int* __restrict__ wzp,
    float* __restrict__ out)
{
    size_t idx = (size_t)blockIdx.x * blockDim.x + threadIdx.x;
    if (idx >= (size_t)M_DIM * N_DIM) return;
    int m = (int)(idx >> 12);
    int o = (int)(idx & 4095);
    float sx = act_scale[0], zx = (float)act_zp[0];
    float sw = wscale[o],    zw = (float)wzp[o];
    float acc = 0.f;
    for (int k = 0; k < K_DIM; ++k) {
        float qx = fminf(fmaxf(rintf(x[(size_t)m * K_DIM + k] / sx) + zx, -128.f), 127.f) - zx;
        float qw = fminf(fmaxf(rintf(w[(size_t)o * K_DIM + k] / sw) + zw, -128.f), 127.f) - zw;
        acc += (qx * sx) * (qw * sw);
    }
    out[idx] = acc + bias[o];
}

// ---------------------------------------------------------------------------
extern "C" void kernel_launch(void* const* d_in, const int* in_sizes, int n_in,
                              void* d_out, int out_size, void* d_ws, size_t ws_size,
                              hipStream_t stream)
{
    const float* x    = (const float*)d_in[0];
    const float* w    = (const float*)d_in[1];
    const float* bias = (const float*)d_in[2];
    const float* asc  = (const float*)d_in[3];
    const float* wsc  = (const float*)d_in[4];
    const int*   azp  = (const int*)d_in[5];
    const int*   wzp  = (const int*)d_in[6];
    float* out = (float*)d_out;

    size_t xq_bytes = (size_t)M_DIM * K_DIM;   // 64 MiB
    size_t wq_bytes = (size_t)N_DIM * K_DIM;   // 16 MiB

    if (ws_size < xq_bytes + wq_bytes) {
        int total = M_DIM * N_DIM;
        fallback_kernel<<<(total + 255) / 256, 256, 0, stream>>>(
            x, w, bias, asc, wsc, azp, wzp, out);
        return;
    }

    signed char* xq = (signed char*)d_ws;
    signed char* wq = (signed char*)d_ws + xq_bytes;

    quant_x_kernel<<<(M_DIM * (K_DIM / 16)) / 256, 256, 0, stream>>>(x, asc, azp, xq);
    quant_w_kernel<<<(N_DIM * (K_DIM / 16)) / 256, 256, 0, stream>>>(w, wsc, wzp, wq);
    gemm_i8_256<<<(M_DIM / 256) * (N_DIM / 256), 512, 0, stream>>>(
        xq, wq, bias, asc, wsc, out);
}